// Round 5
// baseline (859.487 us; speedup 1.0000x reference)
//
#include <hip/hip_runtime.h>
#include <stdint.h>

#define DIM 128
#define LN_EPS 1e-5f
#define NBLK 768
#define NTHR 256

static __device__ __forceinline__ float rlane(float v, int lane) {
    return __uint_as_float(
        (uint32_t)__builtin_amdgcn_readlane((int)__float_as_uint(v), lane));
}

// Grid barrier: one fresh counter per barrier id (zeroed by host memset).
// Release on arrive, acquire on spin; agent scope. All NBLK blocks must call.
static __device__ __forceinline__ void gbar(int* cnts, int id) {
    __syncthreads();
    if (threadIdx.x == 0) {
        __hip_atomic_fetch_add(&cnts[id], 1, __ATOMIC_RELEASE,
                               __HIP_MEMORY_SCOPE_AGENT);
        while (__hip_atomic_load(&cnts[id], __ATOMIC_ACQUIRE,
                                 __HIP_MEMORY_SCOPE_AGENT) < NBLK) {
            __builtin_amdgcn_s_sleep(1);
        }
    }
    __syncthreads();
    __threadfence();   // acquire for all threads (invalidate vL1)
}

// ---------------------------------------------------------------------------
// One dispatch: CSR build (degree/rank -> scan -> fill) + fused
// gather-mean ; h = mean@Wl^T + bl + x@Wr^T ; LayerNorm ; ReLU.
// 768 blocks x 256 thr, <=128 VGPR (4 blk/CU capacity, 3/CU used) so all
// blocks are co-resident and the manual grid barriers are safe.
// ---------------------------------------------------------------------------
__global__ __launch_bounds__(NTHR, 4) void gnn_mega_kernel(
    const float* __restrict__ x,
    const int* __restrict__ ei,
    const float* __restrict__ Wl,
    const float* __restrict__ bl,
    const float* __restrict__ Wr,
    const float* __restrict__ gma,
    const float* __restrict__ bta,
    float* __restrict__ out,
    int* cnts, int* deg, int* offs, int* btot, int* bbase,
    int* rank, int* src_list,
    int N, int E)
{
    __shared__ int lds[NTHR];
    const int t = threadIdx.x;
    const int b = blockIdx.x;
    const int tid = b * NTHR + t;
    const int nthreads = NBLK * NTHR;

    // ---- Phase 1: degree + within-destination rank --------------------------
    for (int e = tid; e < E; e += nthreads) {
        rank[e] = atomicAdd(deg + ei[E + e], 1);
    }
    gbar(cnts, 0);

    // ---- Phase 2a: per-block local exclusive scan of a 66-item chunk --------
    const int C = (N + NBLK - 1) / NBLK;        // 66 for N=50000
    {
        int idx = b * C + t;
        int v = (t < C && idx < N) ? deg[idx] : 0;
        lds[t] = v;
        __syncthreads();
        #pragma unroll
        for (int d = 1; d < NTHR; d <<= 1) {
            int u = (t >= d) ? lds[t - d] : 0;
            __syncthreads();
            lds[t] += u;
            __syncthreads();
        }
        if (t < C && idx < N) offs[idx] = lds[t] - v;   // block-local exclusive
        if (t == NTHR - 1) btot[b] = lds[t];
        __syncthreads();
    }
    gbar(cnts, 1);

    // ---- Phase 2b: block 0 scans the 768 block totals -> bbase --------------
    if (b == 0) {
        const int R = (NBLK + NTHR - 1) / NTHR;  // 3
        int vals[4];
        int s = 0;
        #pragma unroll
        for (int j = 0; j < R; ++j) {
            int i2 = t * R + j;
            vals[j] = (i2 < NBLK) ? btot[i2] : 0;
            s += vals[j];
        }
        lds[t] = s;
        __syncthreads();
        #pragma unroll
        for (int d = 1; d < NTHR; d <<= 1) {
            int u = (t >= d) ? lds[t - d] : 0;
            __syncthreads();
            lds[t] += u;
            __syncthreads();
        }
        int base = lds[t] - s;
        #pragma unroll
        for (int j = 0; j < R; ++j) {
            int i2 = t * R + j;
            if (i2 < NBLK) { bbase[i2] = base; base += vals[j]; }
        }
    }
    gbar(cnts, 2);

    // ---- Phase 2c: add block base ------------------------------------------
    {
        int base = bbase[b];
        int idx = b * C + t;
        if (t < C && idx < N) offs[idx] += base;
    }
    gbar(cnts, 3);

    // ---- Phase 3: fill CSR src lists (plain store, no atomics) --------------
    for (int e = tid; e < E; e += nthreads) {
        src_list[offs[ei[E + e]] + rank[e]] = ei[e];
    }
    gbar(cnts, 4);

    // ---- Phase 4: fused gather-mean + GEMM + LayerNorm + ReLU ---------------
    const int lane = t & 63;
    const int wv = b * (NTHR >> 6) + (t >> 6);
    const int nwaves = NBLK * (NTHR >> 6);
    const int ngroups = (N + 7) / 8;

    const float bl0 = bl[lane];
    const float bl1 = bl[lane + 64];
    const float g0 = gma[lane];
    const float g1 = gma[lane + 64];
    const float be0 = bta[lane];
    const float be1 = bta[lane + 64];

    for (int g = wv; g < ngroups; g += nwaves) {
        const int row0 = g * 8;

        int off_s[8], dg_s[8];
        #pragma unroll
        for (int r = 0; r < 8; ++r) {
            int row = row0 + r;
            bool ok = (row < N);
            int rr = ok ? row : 0;
            off_s[r] = __builtin_amdgcn_readfirstlane(offs[rr]);
            dg_s[r]  = ok ? __builtin_amdgcn_readfirstlane(deg[rr]) : 0;
        }

        float m0[8], m1[8];
        #pragma unroll
        for (int r = 0; r < 8; ++r) { m0[r] = 0.0f; m1[r] = 0.0f; }

        for (int base = 0;; base += 64) {
            int nrem[8], mx = 0;
            #pragma unroll
            for (int r = 0; r < 8; ++r) {
                int u = dg_s[r] - base;
                u = (u < 0) ? 0 : (u > 64 ? 64 : u);
                nrem[r] = u;
                mx = (u > mx) ? u : mx;
            }
            if (mx == 0) break;

            int sidx[8];
            #pragma unroll
            for (int r = 0; r < 8; ++r)
                sidx[r] = (lane < nrem[r]) ? src_list[off_s[r] + base + lane] : 0;

            for (int j = 0; j < mx; ++j) {
                #pragma unroll
                for (int r = 0; r < 8; ++r) {
                    float p = (j < nrem[r]) ? 1.0f : 0.0f;   // wave-uniform
                    int s = __builtin_amdgcn_readlane(sidx[r], j);
                    const float* xr = x + (size_t)s * DIM;
                    m0[r] = fmaf(p, xr[lane], m0[r]);
                    m1[r] = fmaf(p, xr[lane + 64], m1[r]);
                }
            }
        }

        // av[r][j] = a_row[j*64 + lane];  a = concat(mean, x), length 256
        float av[8][4];
        #pragma unroll
        for (int r = 0; r < 8; ++r) {
            int row = row0 + r;
            bool ok = (row < N);
            int rr = ok ? row : 0;
            float rc = (dg_s[r] > 0) ? (1.0f / (float)dg_s[r]) : 0.0f;
            const float* xw = x + (size_t)rr * DIM;
            av[r][0] = m0[r] * rc;
            av[r][1] = m1[r] * rc;
            av[r][2] = ok ? xw[lane] : 0.0f;
            av[r][3] = ok ? xw[lane + 64] : 0.0f;
        }

        float acc0[8], acc1[8];
        #pragma unroll
        for (int r = 0; r < 8; ++r) { acc0[r] = bl0; acc1[r] = bl1; }

        const int d = lane;
        #pragma unroll
        for (int j = 0; j < 4; ++j) {
            const float* Wb = (j < 2) ? Wl : Wr;
            const float4* p0 = (const float4*)(Wb + (size_t)d * DIM + (j & 1) * 64);
            const float4* p1 = (const float4*)(Wb + (size_t)(d + 64) * DIM + (j & 1) * 64);
            #pragma unroll 4
            for (int q = 0; q < 16; ++q) {
                float4 w0 = p0[q];
                float4 w1 = p1[q];
                int kb = q * 4;
                #pragma unroll
                for (int r = 0; r < 8; ++r) {
                    float a0 = rlane(av[r][j], kb + 0);
                    float a1 = rlane(av[r][j], kb + 1);
                    float a2 = rlane(av[r][j], kb + 2);
                    float a3 = rlane(av[r][j], kb + 3);
                    acc0[r] = fmaf(a0, w0.x, acc0[r]);
                    acc1[r] = fmaf(a0, w1.x, acc1[r]);
                    acc0[r] = fmaf(a1, w0.y, acc0[r]);
                    acc1[r] = fmaf(a1, w1.y, acc1[r]);
                    acc0[r] = fmaf(a2, w0.z, acc0[r]);
                    acc1[r] = fmaf(a2, w1.z, acc1[r]);
                    acc0[r] = fmaf(a3, w0.w, acc0[r]);
                    acc1[r] = fmaf(a3, w1.w, acc1[r]);
                }
            }
        }

        #pragma unroll
        for (int r = 0; r < 8; ++r) {
            int row = row0 + r;
            if (row >= N) break;                   // wave-uniform
            float h0 = acc0[r], h1 = acc1[r];
            float s = h0 + h1;
            float q = h0 * h0 + h1 * h1;
            #pragma unroll
            for (int off = 32; off > 0; off >>= 1) {
                s += __shfl_xor(s, off, 64);
                q += __shfl_xor(q, off, 64);
            }
            float mu = s * (1.0f / 128.0f);
            float var = q * (1.0f / 128.0f) - mu * mu;
            float rs = rsqrtf(fmaxf(var, 0.0f) + LN_EPS);
            float o0 = fmaxf((h0 - mu) * rs * g0 + be0, 0.0f);
            float o1 = fmaxf((h1 - mu) * rs * g1 + be1, 0.0f);
            out[(size_t)row * DIM + lane] = o0;
            out[(size_t)row * DIM + lane + 64] = o1;
        }
    }
}

extern "C" void kernel_launch(void* const* d_in, const int* in_sizes, int n_in,
                              void* d_out, int out_size, void* d_ws, size_t ws_size,
                              hipStream_t stream) {
    const float* x  = (const float*)d_in[0];
    const int* ei   = (const int*)d_in[1];
    const float* Wl = (const float*)d_in[2];
    const float* bl = (const float*)d_in[3];
    const float* Wr = (const float*)d_in[4];
    const float* ga = (const float*)d_in[5];
    const float* be = (const float*)d_in[6];
    float* out = (float*)d_out;

    int N = in_sizes[0] / DIM;   // 50000
    int E = in_sizes[1] / 2;     // 600000

    int* cnts     = (int*)d_ws;          // 16 barrier counters
    int* deg      = cnts + 16;           // N
    int* offs     = deg + N;             // N
    int* btot     = offs + N;            // NBLK (pad 1024)
    int* bbase    = btot + 1024;         // NBLK (pad 1024)
    int* rank     = bbase + 1024;        // E
    int* src_list = rank + E;            // E

    // zero only what must start at 0: barrier counters + deg
    hipMemsetAsync(d_ws, 0, (size_t)(16 + N) * sizeof(int), stream);

    gnn_mega_kernel<<<NBLK, NTHR, 0, stream>>>(
        x, ei, Wl, bl, Wr, ga, be, out,
        cnts, deg, offs, btot, bbase, rank, src_list, N, E);
}

// Round 6
// 272.423 us; speedup vs baseline: 3.1550x; 3.1550x over previous
//
#include <hip/hip_runtime.h>
#include <stdint.h>

#define DIM 128
#define LN_EPS 1e-5f
#define SCAN_B 1024

static __device__ __forceinline__ float rlane(float v, int lane) {
    return __uint_as_float(
        (uint32_t)__builtin_amdgcn_readlane((int)__float_as_uint(v), lane));
}

// ---------------------------------------------------------------------------
// K1: degree + within-destination rank (the atomic's return value).
// ---------------------------------------------------------------------------
__global__ __launch_bounds__(256) void degree_rank_kernel(
    const int* __restrict__ ei, int* __restrict__ deg,
    int* __restrict__ rank, int E)
{
    int e = blockIdx.x * blockDim.x + threadIdx.x;
    if (e >= E) return;
    rank[e] = atomicAdd(deg + ei[E + e], 1);
}

// ---------------------------------------------------------------------------
// K2a: block-wise exclusive scan of deg -> offs (block-local), block totals.
// 49 blocks x 1024 threads (multi-block: the R4 single-block scan serialized
// 50k items on one CU and regressed prep — do not repeat).
// ---------------------------------------------------------------------------
__global__ __launch_bounds__(SCAN_B) void scan1_kernel(
    const int* __restrict__ deg, int* __restrict__ offs,
    int* __restrict__ totals, int N)
{
    __shared__ int lds[SCAN_B];
    int t = threadIdx.x, b = blockIdx.x;
    int i = b * SCAN_B + t;
    int v = (i < N) ? deg[i] : 0;
    lds[t] = v;
    __syncthreads();
    #pragma unroll
    for (int d = 1; d < SCAN_B; d <<= 1) {
        int u = (t >= d) ? lds[t - d] : 0;
        __syncthreads();
        lds[t] += u;
        __syncthreads();
    }
    int incl = lds[t];
    if (i < N) offs[i] = incl - v;          // exclusive within block
    if (t == SCAN_B - 1) totals[b] = incl;  // block total
}

// ---------------------------------------------------------------------------
// K2b: add block bases (serial over <=49 totals, redundant per thread).
// ---------------------------------------------------------------------------
__global__ __launch_bounds__(SCAN_B) void scan2_kernel(
    int* __restrict__ offs, const int* __restrict__ totals, int N)
{
    int t = threadIdx.x, b = blockIdx.x;
    int base = 0;
    for (int j = 0; j < b; ++j) base += totals[j];
    int i = b * SCAN_B + t;
    if (i < N) offs[i] += base;
}

// ---------------------------------------------------------------------------
// K3: fill CSR src lists — plain store at offs[dst] + rank[e], no atomics.
// ---------------------------------------------------------------------------
__global__ __launch_bounds__(256) void fill_kernel(
    const int* __restrict__ ei, const int* __restrict__ offs,
    const int* __restrict__ rank, int* __restrict__ src_list, int E)
{
    int e = blockIdx.x * blockDim.x + threadIdx.x;
    if (e >= E) return;
    src_list[offs[ei[E + e]] + rank[e]] = ei[e];
}

// ---------------------------------------------------------------------------
// K4: fused  mean-gather ; h = mean@W_l^T + b_l + x@W_r^T ; LayerNorm ; ReLU
// One wave per 8 rows; lane l owns output features {l, l+64}.
// Gather interleaved across the 8 rows (16 independent loads in flight).
// Byte-identical to the R4 fused kernel that measured 159 us / 52% VALU.
// ---------------------------------------------------------------------------
__global__ __launch_bounds__(256) void fused_kernel(
    const float* __restrict__ x,
    const int* __restrict__ offs,
    const int* __restrict__ deg,
    const int* __restrict__ src_list,
    const float* __restrict__ Wl,
    const float* __restrict__ bl,
    const float* __restrict__ Wr,
    const float* __restrict__ gma,
    const float* __restrict__ bta,
    float* __restrict__ out,
    int N)
{
    const int lane = threadIdx.x & 63;
    const int wave = blockIdx.x * (blockDim.x >> 6) + (threadIdx.x >> 6);
    const int row0 = wave * 8;
    if (row0 >= N) return;

    int off_s[8], dg_s[8];
    #pragma unroll
    for (int r = 0; r < 8; ++r) {
        int row = row0 + r;
        bool ok = (row < N);
        int rr = ok ? row : 0;
        off_s[r] = __builtin_amdgcn_readfirstlane(offs[rr]);
        dg_s[r]  = ok ? __builtin_amdgcn_readfirstlane(deg[rr]) : 0;
    }

    float m0[8], m1[8];
    #pragma unroll
    for (int r = 0; r < 8; ++r) { m0[r] = 0.0f; m1[r] = 0.0f; }

    for (int base = 0;; base += 64) {
        int nrem[8], mx = 0;
        #pragma unroll
        for (int r = 0; r < 8; ++r) {
            int t = dg_s[r] - base;
            t = (t < 0) ? 0 : (t > 64 ? 64 : t);
            nrem[r] = t;
            mx = (t > mx) ? t : mx;
        }
        if (mx == 0) break;

        int sidx[8];
        #pragma unroll
        for (int r = 0; r < 8; ++r)
            sidx[r] = (lane < nrem[r]) ? src_list[off_s[r] + base + lane] : 0;

        for (int j = 0; j < mx; ++j) {
            #pragma unroll
            for (int r = 0; r < 8; ++r) {
                float p = (j < nrem[r]) ? 1.0f : 0.0f;   // wave-uniform
                int s = __builtin_amdgcn_readlane(sidx[r], j);
                const float* xr = x + (size_t)s * DIM;
                m0[r] = fmaf(p, xr[lane], m0[r]);
                m1[r] = fmaf(p, xr[lane + 64], m1[r]);
            }
        }
    }

    // av[r][j] = a_row[j*64 + lane];  a = concat(mean, x), length 256
    float av[8][4];
    #pragma unroll
    for (int r = 0; r < 8; ++r) {
        int row = row0 + r;
        bool ok = (row < N);
        int rr = ok ? row : 0;
        float rc = (dg_s[r] > 0) ? (1.0f / (float)dg_s[r]) : 0.0f;
        const float* xw = x + (size_t)rr * DIM;
        av[r][0] = m0[r] * rc;
        av[r][1] = m1[r] * rc;
        av[r][2] = ok ? xw[lane] : 0.0f;
        av[r][3] = ok ? xw[lane + 64] : 0.0f;
    }

    const float bl0 = bl[lane];
    const float bl1 = bl[lane + 64];
    float acc0[8], acc1[8];
    #pragma unroll
    for (int r = 0; r < 8; ++r) { acc0[r] = bl0; acc1[r] = bl1; }

    const int d = lane;
    #pragma unroll
    for (int j = 0; j < 4; ++j) {
        const float* Wb = (j < 2) ? Wl : Wr;
        const float4* p0 = (const float4*)(Wb + (size_t)d * DIM + (j & 1) * 64);
        const float4* p1 = (const float4*)(Wb + (size_t)(d + 64) * DIM + (j & 1) * 64);
        #pragma unroll 4
        for (int q = 0; q < 16; ++q) {
            float4 w0 = p0[q];
            float4 w1 = p1[q];
            int kb = q * 4;
            #pragma unroll
            for (int r = 0; r < 8; ++r) {
                float a0 = rlane(av[r][j], kb + 0);
                float a1 = rlane(av[r][j], kb + 1);
                float a2 = rlane(av[r][j], kb + 2);
                float a3 = rlane(av[r][j], kb + 3);
                acc0[r] = fmaf(a0, w0.x, acc0[r]);
                acc1[r] = fmaf(a0, w1.x, acc1[r]);
                acc0[r] = fmaf(a1, w0.y, acc0[r]);
                acc1[r] = fmaf(a1, w1.y, acc1[r]);
                acc0[r] = fmaf(a2, w0.z, acc0[r]);
                acc1[r] = fmaf(a2, w1.z, acc1[r]);
                acc0[r] = fmaf(a3, w0.w, acc0[r]);
                acc1[r] = fmaf(a3, w1.w, acc1[r]);
            }
        }
    }

    const float g0 = gma[lane];
    const float g1 = gma[lane + 64];
    const float be0 = bta[lane];
    const float be1 = bta[lane + 64];

    #pragma unroll
    for (int r = 0; r < 8; ++r) {
        int row = row0 + r;
        if (row >= N) break;                       // wave-uniform
        float h0 = acc0[r], h1 = acc1[r];
        float s = h0 + h1;
        float q = h0 * h0 + h1 * h1;
        #pragma unroll
        for (int off = 32; off > 0; off >>= 1) {
            s += __shfl_xor(s, off, 64);
            q += __shfl_xor(q, off, 64);
        }
        float mu = s * (1.0f / 128.0f);
        float var = q * (1.0f / 128.0f) - mu * mu;
        float rs = rsqrtf(fmaxf(var, 0.0f) + LN_EPS);
        float o0 = fmaxf((h0 - mu) * rs * g0 + be0, 0.0f);
        float o1 = fmaxf((h1 - mu) * rs * g1 + be1, 0.0f);
        out[(size_t)row * DIM + lane] = o0;
        out[(size_t)row * DIM + lane + 64] = o1;
    }
}

extern "C" void kernel_launch(void* const* d_in, const int* in_sizes, int n_in,
                              void* d_out, int out_size, void* d_ws, size_t ws_size,
                              hipStream_t stream) {
    const float* x  = (const float*)d_in[0];
    const int* ei   = (const int*)d_in[1];
    const float* Wl = (const float*)d_in[2];
    const float* bl = (const float*)d_in[3];
    const float* Wr = (const float*)d_in[4];
    const float* ga = (const float*)d_in[5];
    const float* be = (const float*)d_in[6];
    float* out = (float*)d_out;

    int N = in_sizes[0] / DIM;   // 50000
    int E = in_sizes[1] / 2;     // 600000
    int nb = (N + SCAN_B - 1) / SCAN_B;   // 49

    int* deg      = (int*)d_ws;          // N
    int* offs     = deg + N;             // N
    int* totals   = offs + N;            // nb (pad 64)
    int* rank     = totals + ((nb + 63) & ~63);  // E
    int* src_list = rank + E;            // E

    hipMemsetAsync(deg, 0, (size_t)N * sizeof(int), stream);

    degree_rank_kernel<<<(E + 255) / 256, 256, 0, stream>>>(ei, deg, rank, E);
    scan1_kernel<<<nb, SCAN_B, 0, stream>>>(deg, offs, totals, N);
    scan2_kernel<<<nb, SCAN_B, 0, stream>>>(offs, totals, N);
    fill_kernel<<<(E + 255) / 256, 256, 0, stream>>>(ei, offs, rank, src_list, E);

    {
        int waves = (N + 7) / 8;
        int blocks = (waves + 3) / 4;
        fused_kernel<<<blocks, 256, 0, stream>>>(x, offs, deg, src_list,
                                                 Wl, bl, Wr, ga, be, out, N);
    }
}